// Round 1
// baseline (467.091 us; speedup 1.0000x reference)
//
#include <hip/hip_runtime.h>
#include <hip/hip_bf16.h>
#include <hip/hip_fp16.h>

#define B_ 16
#define S_ 2048
#define D_ 128
#define SPAD 8
#define SROW (S_ + SPAD)   // padded f16 score row: 2056

typedef __attribute__((ext_vector_type(8))) short short8;   // 8 x bf16 MFMA frag
typedef __attribute__((ext_vector_type(4))) float f32x4;    // MFMA accumulator
typedef __attribute__((ext_vector_type(4))) unsigned short u16x4;

__device__ __forceinline__ unsigned short f2bf(float f) {
  unsigned int u = __builtin_bit_cast(unsigned int, f);
  unsigned int r = (u + 0x7fffu + ((u >> 16) & 1u)) >> 16;   // RNE
  return (unsigned short)r;
}

// ---------- prep: fp32 -> bf16 ----------
__global__ void cvt_bf16_kernel(const float* __restrict__ x,
                                unsigned short* __restrict__ y, int n4) {
  int i = blockIdx.x * blockDim.x + threadIdx.x;
  if (i >= n4) return;
  float4 f = reinterpret_cast<const float4*>(x)[i];
  u16x4 o;
  o[0] = f2bf(f.x); o[1] = f2bf(f.y); o[2] = f2bf(f.z); o[3] = f2bf(f.w);
  reinterpret_cast<u16x4*>(y)[i] = o;
}

// ---------- prep: V [b][k][d] fp32 -> V^T [b][d][k] bf16 ----------
__global__ void vtrans_kernel(const float* __restrict__ v,
                              unsigned short* __restrict__ vT) {
  __shared__ float tile[32][33];
  int b = blockIdx.z, kt = blockIdx.x, dt = blockIdx.y;
  int t = threadIdx.x;
  int c = t & 31, r0 = t >> 5;
  const float* src = v + ((size_t)b * S_ + (size_t)kt * 32) * D_ + dt * 32;
#pragma unroll
  for (int i = 0; i < 4; i++) {
    int r = r0 + 8 * i;
    tile[r][c] = src[(size_t)r * D_ + c];
  }
  __syncthreads();
  unsigned short* dst = vT + ((size_t)b * D_ + dt * 32) * S_ + (size_t)kt * 32;
#pragma unroll
  for (int i = 0; i < 4; i++) {
    int r = r0 + 8 * i;
    dst[(size_t)r * S_ + c] = f2bf(tile[c][r]);
  }
}

// ---------- main attention kernel ----------
// 1 block = 8 waves = 512 threads, handles 32 q-rows of one batch.
__global__ __launch_bounds__(512, 1)
void attn_main_kernel(const unsigned short* __restrict__ qbf,
                      const unsigned short* __restrict__ kbf,
                      const unsigned short* __restrict__ vT,
                      const void* __restrict__ maskp,
                      const float* __restrict__ scalep,
                      float* __restrict__ ctx,
                      float* __restrict__ att) {
  __shared__ unsigned short s_lds[32][SROW];   // f16 scores -> later bf16 probs (128.5 KB)
  __shared__ unsigned short q_lds[32 * 128];   // swizzled bf16 Q tile (8 KB)
  __shared__ float red_m[4][32];
  __shared__ float red_Z[4][32];
  __shared__ float sm_m[32];
  __shared__ float sm_iz[32];

  const int tid = threadIdx.x;
  const int b  = blockIdx.x >> 6;
  const int q0 = (blockIdx.x & 63) << 5;

  // --- mask layout detection: bool bytes vs int32 (deterministic for fixed input) ---
  int myv = 0;
  if (tid < 256) myv = (reinterpret_cast<const unsigned int*>(maskp)[tid] > 1u) ? 1 : 0;
  const int mask_is_byte = __syncthreads_or(myv);

  const float scale = scalep[0];

  const int w   = tid >> 6;    // wave 0..7
  const int l   = tid & 63;
  const int l16 = l & 15;
  const int lq  = l >> 4;      // quarter-wave 0..3

  // --- stage Q tile (bf16, XOR-swizzled rows for conflict-free b128 frag reads) ---
  {
    int row = tid >> 4;              // 0..31
    int col = (tid & 15) << 3;       // 0..120 step 8
    short8 qv = *reinterpret_cast<const short8*>(
        qbf + (((size_t)(b * S_ + q0 + row)) << 7) + col);
    int byte = row * 256 + ((col * 2) ^ ((row & 7) << 4));
    *reinterpret_cast<short8*>(reinterpret_cast<char*>(q_lds) + byte) = qv;
  }
  __syncthreads();

  // wave -> (row half, 512-col chunk)
  const int mrow  = w & 1;
  const int chunk = w >> 1;

  // A-frags (Q) for the wave's 16 rows, all 4 k-steps of D=128; held in regs all pass A
  short8 afr[4];
  {
    int arow = mrow * 16 + l16;
#pragma unroll
    for (int ks = 0; ks < 4; ks++) {
      int cb = (lq * 8 + ks * 32) * 2;
      int byte = arow * 256 + (cb ^ ((arow & 7) << 4));
      afr[ks] = *reinterpret_cast<const short8*>(
          reinterpret_cast<const char*>(q_lds) + byte);
    }
  }

  float m_run[4], Z_run[4];
#pragma unroll
  for (int r = 0; r < 4; r++) { m_run[r] = -1e30f; Z_run[r] = 0.0f; }

  const unsigned short* kb_base = kbf + (((size_t)b * S_) << 7);
  const unsigned char* mask8 = reinterpret_cast<const unsigned char*>(maskp);
  const int* mask32 = reinterpret_cast<const int*>(maskp);
  const size_t mbase = ((size_t)b * S_ + q0) * S_;

  // --- pass A: S = (Q K^T)*scale, mask, f16 -> LDS, online (m, Z) per row ---
  for (int c16 = 0; c16 < 32; c16++) {
    const int colb = chunk * 512 + c16 * 16;
    const int colg = colb + l16;       // this lane's S-column == its K-row for B-frag
    f32x4 acc = {0.f, 0.f, 0.f, 0.f};
    const unsigned short* krow = kb_base + (((size_t)colg) << 7) + lq * 8;
#pragma unroll
    for (int ks = 0; ks < 4; ks++) {
      short8 bfr = *reinterpret_cast<const short8*>(krow + ks * 32);
      acc = __builtin_amdgcn_mfma_f32_16x16x32_bf16(afr[ks], bfr, acc, 0, 0, 0);
    }
#pragma unroll
    for (int r = 0; r < 4; r++) {
      const int row = mrow * 16 + lq * 4 + r;
      float s = acc[r] * scale;
      const size_t mi = mbase + (size_t)row * S_ + colg;
      bool masked = mask_is_byte ? (mask8[mi] != 0) : (mask32[mi] != 0);
      if (masked) s = -INFINITY;
      float nm = fmaxf(m_run[r], s);
      Z_run[r] = Z_run[r] * __expf(m_run[r] - nm) + __expf(s - nm);
      m_run[r] = nm;
      s_lds[row][colg] = __half_as_ushort(__float2half(s));
    }
  }

  // --- reduce (m, Z) across the 16 col-lanes, then across the 4 col-chunks ---
#pragma unroll
  for (int r = 0; r < 4; r++) {
    float m = m_run[r], Z = Z_run[r];
#pragma unroll
    for (int off = 1; off < 16; off <<= 1) {
      float mo = __shfl_xor(m, off, 64);
      float Zo = __shfl_xor(Z, off, 64);
      float nm = fmaxf(m, mo);
      Z = Z * __expf(m - nm) + Zo * __expf(mo - nm);
      m = nm;
    }
    if (l16 == 0) {
      int row = mrow * 16 + lq * 4 + r;
      red_m[chunk][row] = m;
      red_Z[chunk][row] = Z;
    }
  }
  __syncthreads();

  {
    int row = tid & 31;
    float m0 = red_m[0][row], m1 = red_m[1][row];
    float m2 = red_m[2][row], m3 = red_m[3][row];
    float m = fmaxf(fmaxf(m0, m1), fmaxf(m2, m3));
    float Z = red_Z[0][row] * __expf(m0 - m) + red_Z[1][row] * __expf(m1 - m)
            + red_Z[2][row] * __expf(m2 - m) + red_Z[3][row] * __expf(m3 - m);
    if (tid < 32) { sm_m[row] = m; sm_iz[row] = 1.0f / Z; }
  }
  __syncthreads();

  // --- pass C1: p = exp(s-m)/Z -> fp32 attention out; overwrite LDS with bf16 p ---
  {
#pragma unroll
    for (int rr = 0; rr < 4; rr++) {
      const int row = w + rr * 8;
      const float m = sm_m[row];
      const float iz = sm_iz[row];
      float* arow = att + ((size_t)b * S_ + q0 + row) * S_;
#pragma unroll
      for (int it = 0; it < 8; it++) {
        const int col = it * 256 + l * 4;
        __half2 h01 = *reinterpret_cast<const __half2*>(&s_lds[row][col]);
        __half2 h23 = *reinterpret_cast<const __half2*>(&s_lds[row][col + 2]);
        float2 f01 = __half22float2(h01);
        float2 f23 = __half22float2(h23);
        float p0 = __expf(f01.x - m) * iz;
        float p1 = __expf(f01.y - m) * iz;
        float p2 = __expf(f23.x - m) * iz;
        float p3 = __expf(f23.y - m) * iz;
        *reinterpret_cast<float4*>(arow + col) = make_float4(p0, p1, p2, p3);
        u16x4 pb;
        pb[0] = f2bf(p0); pb[1] = f2bf(p1); pb[2] = f2bf(p2); pb[3] = f2bf(p3);
        *reinterpret_cast<u16x4*>(&s_lds[row][col]) = pb;
      }
    }
  }
  __syncthreads();

  // --- pass C2: context = P V  (P bf16 from LDS, V^T bf16 from global/L2) ---
  {
    const unsigned short* vrow =
        vT + ((size_t)b * D_ + w * 16 + l16) * S_ + lq * 8;
    const char* pb0 = reinterpret_cast<const char*>(&s_lds[l16][0]);
    const char* pb1 = reinterpret_cast<const char*>(&s_lds[l16 + 16][0]);
    f32x4 acc0 = {0.f, 0.f, 0.f, 0.f}, acc1 = {0.f, 0.f, 0.f, 0.f};
    for (int ks = 0; ks < 64; ks++) {
      const int kb = (lq * 8 + ks * 32) * 2;
      short8 a0 = *reinterpret_cast<const short8*>(pb0 + kb);
      short8 a1 = *reinterpret_cast<const short8*>(pb1 + kb);
      short8 bv = *reinterpret_cast<const short8*>(vrow + ks * 32);
      acc0 = __builtin_amdgcn_mfma_f32_16x16x32_bf16(a0, bv, acc0, 0, 0, 0);
      acc1 = __builtin_amdgcn_mfma_f32_16x16x32_bf16(a1, bv, acc1, 0, 0, 0);
    }
    float* cbase = ctx + ((size_t)b * S_ + q0) * D_ + w * 16 + l16;
#pragma unroll
    for (int r = 0; r < 4; r++) {
      cbase[(size_t)(lq * 4 + r) * D_]      = acc0[r];
      cbase[(size_t)(lq * 4 + r + 16) * D_] = acc1[r];
    }
  }
}

extern "C" void kernel_launch(void* const* d_in, const int* in_sizes, int n_in,
                              void* d_out, int out_size, void* d_ws, size_t ws_size,
                              hipStream_t stream) {
  (void)in_sizes; (void)n_in; (void)out_size; (void)ws_size;
  const float* q = (const float*)d_in[0];
  const float* k = (const float*)d_in[1];
  const float* v = (const float*)d_in[2];
  const float* scale = (const float*)d_in[3];
  const void* mask = d_in[4];

  unsigned short* qbf = (unsigned short*)d_ws;                  // 8 MB
  unsigned short* kbf = qbf + (size_t)B_ * S_ * D_;             // 8 MB
  unsigned short* vTb = kbf + (size_t)B_ * S_ * D_;             // 8 MB

  float* ctx = (float*)d_out;                                   // [B,S,D]
  float* att = ctx + (size_t)B_ * S_ * D_;                      // [B,S,S]

  const int n4 = B_ * S_ * D_ / 4;
  cvt_bf16_kernel<<<dim3((n4 + 255) / 256), dim3(256), 0, stream>>>(q, qbf, n4);
  cvt_bf16_kernel<<<dim3((n4 + 255) / 256), dim3(256), 0, stream>>>(k, kbf, n4);
  vtrans_kernel<<<dim3(S_ / 32, D_ / 32, B_), dim3(256), 0, stream>>>(v, vTb);
  attn_main_kernel<<<dim3(B_ * (S_ / 32)), dim3(512), 0, stream>>>(
      qbf, kbf, vTb, mask, scale, ctx, att);
}

// Round 2
// 311.886 us; speedup vs baseline: 1.4976x; 1.4976x over previous
//
#include <hip/hip_runtime.h>
#include <hip/hip_bf16.h>
#include <hip/hip_fp16.h>

#define B_ 16
#define S_ 2048
#define D_ 128
#define QB 16
#define SPAD 8
#define SROW (S_ + SPAD)   // padded f16/bf16 score row: 2056

typedef __attribute__((ext_vector_type(8))) short short8;   // 8 x bf16 MFMA frag
typedef __attribute__((ext_vector_type(4))) float f32x4;    // MFMA accumulator
typedef __attribute__((ext_vector_type(4))) unsigned short u16x4;

__device__ __forceinline__ unsigned short f2bf(float f) {
  unsigned int u = __builtin_bit_cast(unsigned int, f);
  unsigned int r = (u + 0x7fffu + ((u >> 16) & 1u)) >> 16;   // RNE
  return (unsigned short)r;
}

// ---------- prep: fp32 -> bf16 (optionally scaled; sc==nullptr -> 1.0) ----------
__global__ void cvt_bf16_kernel(const float* __restrict__ x,
                                unsigned short* __restrict__ y,
                                const float* __restrict__ sc, int n4) {
  int i = blockIdx.x * blockDim.x + threadIdx.x;
  if (i >= n4) return;
  float s = sc ? sc[0] : 1.0f;
  float4 f = reinterpret_cast<const float4*>(x)[i];
  u16x4 o;
  o[0] = f2bf(f.x * s); o[1] = f2bf(f.y * s);
  o[2] = f2bf(f.z * s); o[3] = f2bf(f.w * s);
  reinterpret_cast<u16x4*>(y)[i] = o;
}

// ---------- prep: V [b][k][d] fp32 -> V^T [b][d][k] bf16 ----------
__global__ void vtrans_kernel(const float* __restrict__ v,
                              unsigned short* __restrict__ vT) {
  __shared__ float tile[32][33];
  int b = blockIdx.z, kt = blockIdx.x, dt = blockIdx.y;
  int t = threadIdx.x;
  int c = t & 31, r0 = t >> 5;
  const float* src = v + ((size_t)b * S_ + (size_t)kt * 32) * D_ + dt * 32;
#pragma unroll
  for (int i = 0; i < 4; i++) {
    int r = r0 + 8 * i;
    tile[r][c] = src[(size_t)r * D_ + c];
  }
  __syncthreads();
  unsigned short* dst = vT + ((size_t)b * D_ + dt * 32) * S_ + (size_t)kt * 32;
#pragma unroll
  for (int i = 0; i < 4; i++) {
    int r = r0 + 8 * i;
    dst[(size_t)r * S_ + c] = f2bf(tile[c][r]);
  }
}

// ---------- main attention kernel ----------
// 1 block = 8 waves = 512 threads, 16 q-rows of one batch. 2 blocks/CU (70 KB LDS).
__global__ __launch_bounds__(512, 4)
void attn_main_kernel(const unsigned short* __restrict__ qbf,   // scale pre-folded
                      const unsigned short* __restrict__ kbf,
                      const unsigned short* __restrict__ vT,
                      const void* __restrict__ maskp,
                      float* __restrict__ ctx,
                      float* __restrict__ att) {
  __shared__ unsigned short s_lds[QB][SROW];   // f16 scores -> later bf16 probs (64.25 KB)
  __shared__ unsigned short q_lds[QB * 128];   // swizzled bf16 Q tile (4 KB)

  const int tid = threadIdx.x;
  const int b  = blockIdx.x >> 7;
  const int q0 = (blockIdx.x & 127) << 4;

  // --- mask layout detection: bool bytes vs int32 (deterministic for fixed input) ---
  int myv = 0;
  if (tid < 256) myv = (reinterpret_cast<const unsigned int*>(maskp)[tid] > 1u) ? 1 : 0;
  const int mask_is_byte = __syncthreads_or(myv);

  const int w   = tid >> 6;    // wave 0..7
  const int l   = tid & 63;
  const int l16 = l & 15;
  const int lq  = l >> 4;      // quarter-wave 0..3

  // --- stage Q tile (bf16, XOR-swizzled rows for conflict-free b128 frag reads) ---
  {
    int row = tid >> 5;              // 0..15
    int col = (tid & 31) << 2;       // 0..124 step 4
    u16x4 qv = *reinterpret_cast<const u16x4*>(
        qbf + (((size_t)(b * S_ + q0 + row)) << 7) + col);
    int byte = row * 256 + ((col * 2) ^ ((row & 7) << 4));
    *reinterpret_cast<u16x4*>(reinterpret_cast<char*>(q_lds) + byte) = qv;
  }
  __syncthreads();

  // --- Q B-frags (held in regs for all of pass A) ---
  short8 qf[4];
  {
    int qrow = l16;
#pragma unroll
    for (int ks = 0; ks < 4; ks++) {
      int cb = (lq * 8 + ks * 32) * 2;
      int byte = qrow * 256 + (cb ^ ((qrow & 7) << 4));
      qf[ks] = *reinterpret_cast<const short8*>(
          reinterpret_cast<const char*>(q_lds) + byte);
    }
  }

  const unsigned short* kb = kbf + (((size_t)b * S_) << 7);

  // --- pass A: S^T-fragment MFMA (A=K, B=Q) -> packed f16 score writes ---
  // Lane holds 4 CONSECUTIVE score-columns of one q-row -> single b64 LDS write.
  short8 kf[4];
  {
    const unsigned short* kp = kb + (((size_t)(w * 16 + l16)) << 7) + lq * 8;
#pragma unroll
    for (int ks = 0; ks < 4; ks++)
      kf[ks] = *reinterpret_cast<const short8*>(kp + ks * 32);
  }
  for (int it = 0; it < 16; ++it) {
    short8 kn[4];
    if (it < 15) {
      const unsigned short* kp =
          kb + (((size_t)((it + 1) * 128 + w * 16 + l16)) << 7) + lq * 8;
#pragma unroll
      for (int ks = 0; ks < 4; ks++)
        kn[ks] = *reinterpret_cast<const short8*>(kp + ks * 32);
    }
    f32x4 acc = {0.f, 0.f, 0.f, 0.f};
#pragma unroll
    for (int ks = 0; ks < 4; ks++)
      acc = __builtin_amdgcn_mfma_f32_16x16x32_bf16(kf[ks], qf[ks], acc, 0, 0, 0);
    // D[row=score-col = (l>>4)*4+r][col=q-row = l&15]
    int col = it * 128 + w * 16 + lq * 4;
    u16x4 h;
#pragma unroll
    for (int r = 0; r < 4; r++)
      h[r] = __half_as_ushort(__float2half(acc[r]));
    *reinterpret_cast<u16x4*>(&s_lds[l16][col]) = h;
    if (it < 15) {
#pragma unroll
      for (int ks = 0; ks < 4; ks++) kf[ks] = kn[ks];
    }
  }
  __syncthreads();

  // --- fused row pass: mask, max, exp once, Z, att write, bf16 P -> LDS ---
  const unsigned char* mask8 = reinterpret_cast<const unsigned char*>(maskp);
  const int* mask32 = reinterpret_cast<const int*>(maskp);
#pragma unroll
  for (int rr = 0; rr < 2; ++rr) {
    const int row = w * 2 + rr;
    const size_t mrow = ((size_t)b * S_ + q0 + row) * S_;
    float s32[32];
    if (mask_is_byte) {
#pragma unroll
      for (int it = 0; it < 8; ++it) {
        const int col = it * 256 + l * 4;
        uint2 sv = *reinterpret_cast<const uint2*>(&s_lds[row][col]);
        unsigned int mv = *reinterpret_cast<const unsigned int*>(mask8 + mrow + col);
        float2 f01 = __half22float2(__builtin_bit_cast(__half2, sv.x));
        float2 f23 = __half22float2(__builtin_bit_cast(__half2, sv.y));
        s32[it * 4 + 0] = (mv & 0x000000ffu) ? -INFINITY : f01.x;
        s32[it * 4 + 1] = (mv & 0x0000ff00u) ? -INFINITY : f01.y;
        s32[it * 4 + 2] = (mv & 0x00ff0000u) ? -INFINITY : f23.x;
        s32[it * 4 + 3] = (mv & 0xff000000u) ? -INFINITY : f23.y;
      }
    } else {
#pragma unroll
      for (int it = 0; it < 8; ++it) {
        const int col = it * 256 + l * 4;
        uint2 sv = *reinterpret_cast<const uint2*>(&s_lds[row][col]);
        int4 mi = *reinterpret_cast<const int4*>(mask32 + mrow + col);
        float2 f01 = __half22float2(__builtin_bit_cast(__half2, sv.x));
        float2 f23 = __half22float2(__builtin_bit_cast(__half2, sv.y));
        s32[it * 4 + 0] = mi.x ? -INFINITY : f01.x;
        s32[it * 4 + 1] = mi.y ? -INFINITY : f01.y;
        s32[it * 4 + 2] = mi.z ? -INFINITY : f23.x;
        s32[it * 4 + 3] = mi.w ? -INFINITY : f23.y;
      }
    }
    float m = s32[0];
#pragma unroll
    for (int j = 1; j < 32; ++j) m = fmaxf(m, s32[j]);
#pragma unroll
    for (int off = 1; off < 64; off <<= 1) m = fmaxf(m, __shfl_xor(m, off, 64));
    float Z = 0.0f;
#pragma unroll
    for (int j = 0; j < 32; ++j) {
      float e = __expf(s32[j] - m);
      s32[j] = e;
      Z += e;
    }
#pragma unroll
    for (int off = 1; off < 64; off <<= 1) Z += __shfl_xor(Z, off, 64);
    const float iz = 1.0f / Z;
    float* arow = att + mrow;
#pragma unroll
    for (int it = 0; it < 8; ++it) {
      const int col = it * 256 + l * 4;
      float p0 = s32[it * 4 + 0] * iz;
      float p1 = s32[it * 4 + 1] * iz;
      float p2 = s32[it * 4 + 2] * iz;
      float p3 = s32[it * 4 + 3] * iz;
      *reinterpret_cast<float4*>(arow + col) = make_float4(p0, p1, p2, p3);
      u16x4 pb;
      pb[0] = f2bf(p0); pb[1] = f2bf(p1); pb[2] = f2bf(p2); pb[3] = f2bf(p3);
      *reinterpret_cast<u16x4*>(&s_lds[row][col]) = pb;
    }
  }
  __syncthreads();

  // --- pass C2: context = P V  (P bf16 from LDS, V^T bf16 from global/L2) ---
  {
    const unsigned short* vrow =
        vT + ((size_t)(b * D_ + w * 16 + l16)) * S_ + lq * 8;
    const char* prow = reinterpret_cast<const char*>(&s_lds[l16][0]);
    f32x4 acc0 = {0.f, 0.f, 0.f, 0.f}, acc1 = {0.f, 0.f, 0.f, 0.f};
#pragma unroll 8
    for (int ks = 0; ks < 64; ks += 2) {
      short8 a0 = *reinterpret_cast<const short8*>(prow + (lq * 8 + ks * 32) * 2);
      short8 b0 = *reinterpret_cast<const short8*>(vrow + ks * 32);
      acc0 = __builtin_amdgcn_mfma_f32_16x16x32_bf16(a0, b0, acc0, 0, 0, 0);
      short8 a1 = *reinterpret_cast<const short8*>(prow + (lq * 8 + (ks + 1) * 32) * 2);
      short8 b1 = *reinterpret_cast<const short8*>(vrow + (ks + 1) * 32);
      acc1 = __builtin_amdgcn_mfma_f32_16x16x32_bf16(a1, b1, acc1, 0, 0, 0);
    }
    float* cb = ctx + ((size_t)(b * S_ + q0)) * D_ + w * 16 + l16;
#pragma unroll
    for (int r = 0; r < 4; r++)
      cb[(size_t)(lq * 4 + r) * D_] = acc0[r] + acc1[r];
  }
}

extern "C" void kernel_launch(void* const* d_in, const int* in_sizes, int n_in,
                              void* d_out, int out_size, void* d_ws, size_t ws_size,
                              hipStream_t stream) {
  (void)in_sizes; (void)n_in; (void)out_size; (void)ws_size;
  const float* q = (const float*)d_in[0];
  const float* k = (const float*)d_in[1];
  const float* v = (const float*)d_in[2];
  const float* scale = (const float*)d_in[3];
  const void* mask = d_in[4];

  unsigned short* qbf = (unsigned short*)d_ws;                  // 8 MB
  unsigned short* kbf = qbf + (size_t)B_ * S_ * D_;             // 8 MB
  unsigned short* vTb = kbf + (size_t)B_ * S_ * D_;             // 8 MB

  float* ctx = (float*)d_out;                                   // [B,S,D]
  float* att = ctx + (size_t)B_ * S_ * D_;                      // [B,S,S]

  const int n4 = B_ * S_ * D_ / 4;
  cvt_bf16_kernel<<<dim3((n4 + 255) / 256), dim3(256), 0, stream>>>(q, qbf, scale, n4);
  cvt_bf16_kernel<<<dim3((n4 + 255) / 256), dim3(256), 0, stream>>>(k, kbf, nullptr, n4);
  vtrans_kernel<<<dim3(S_ / 32, D_ / 32, B_), dim3(256), 0, stream>>>(v, vTb);
  attn_main_kernel<<<dim3(B_ * (S_ / QB)), dim3(512), 0, stream>>>(
      qbf, kbf, vTb, mask, ctx, att);
}

// Round 4
// 301.714 us; speedup vs baseline: 1.5481x; 1.0337x over previous
//
#include <hip/hip_runtime.h>
#include <hip/hip_bf16.h>
#include <hip/hip_fp16.h>

#define B_ 16
#define S_ 2048
#define D_ 128
#define QB 16
#define SPAD 8
#define SROW (S_ + SPAD)   // padded f16/bf16 score row: 2056

typedef __attribute__((ext_vector_type(8))) short short8;   // 8 x bf16 MFMA frag
typedef __attribute__((ext_vector_type(4))) float f32x4;    // MFMA accumulator
typedef __attribute__((ext_vector_type(4))) float f32x4v;   // vector float4 (builtins-ok)
typedef __attribute__((ext_vector_type(4))) int i32x4;      // vector int4 (builtins-ok)
typedef __attribute__((ext_vector_type(4))) unsigned short u16x4;

__device__ __forceinline__ unsigned short f2bf(float f) {
  unsigned int u = __builtin_bit_cast(unsigned int, f);
  unsigned int r = (u + 0x7fffu + ((u >> 16) & 1u)) >> 16;   // RNE
  return (unsigned short)r;
}

// ---------- prep: fp32 -> bf16 (optionally scaled; sc==nullptr -> 1.0) ----------
__global__ void cvt_bf16_kernel(const float* __restrict__ x,
                                unsigned short* __restrict__ y,
                                const float* __restrict__ sc, int n4) {
  int i = blockIdx.x * blockDim.x + threadIdx.x;
  if (i >= n4) return;
  float s = sc ? sc[0] : 1.0f;
  float4 f = reinterpret_cast<const float4*>(x)[i];
  u16x4 o;
  o[0] = f2bf(f.x * s); o[1] = f2bf(f.y * s);
  o[2] = f2bf(f.z * s); o[3] = f2bf(f.w * s);
  reinterpret_cast<u16x4*>(y)[i] = o;
}

// ---------- prep: V [b][k][d] fp32 -> V^T [b][d][k] bf16 ----------
__global__ void vtrans_kernel(const float* __restrict__ v,
                              unsigned short* __restrict__ vT) {
  __shared__ float tile[32][33];
  int b = blockIdx.z, kt = blockIdx.x, dt = blockIdx.y;
  int t = threadIdx.x;
  int c = t & 31, r0 = t >> 5;
  const float* src = v + ((size_t)b * S_ + (size_t)kt * 32) * D_ + dt * 32;
#pragma unroll
  for (int i = 0; i < 4; i++) {
    int r = r0 + 8 * i;
    tile[r][c] = src[(size_t)r * D_ + c];
  }
  __syncthreads();
  unsigned short* dst = vT + ((size_t)b * D_ + dt * 32) * S_ + (size_t)kt * 32;
#pragma unroll
  for (int i = 0; i < 4; i++) {
    int r = r0 + 8 * i;
    dst[(size_t)r * S_ + c] = f2bf(tile[c][r]);
  }
}

// ---------- main attention kernel ----------
// 1 block = 8 waves = 512 threads, 16 q-rows of one batch. 2 blocks/CU (70 KB LDS).
__global__ __launch_bounds__(512, 4)
void attn_main_kernel(const unsigned short* __restrict__ qbf,   // scale pre-folded
                      const unsigned short* __restrict__ kbf,
                      const unsigned short* __restrict__ vT,
                      const void* __restrict__ maskp,
                      float* __restrict__ ctx,
                      float* __restrict__ att) {
  __shared__ unsigned short s_lds[QB][SROW];   // f16 scores -> later bf16 probs (64.25 KB)
  __shared__ unsigned short q_lds[QB * 128];   // swizzled bf16 Q tile (4 KB)

  const int tid = threadIdx.x;
  const int b  = blockIdx.x >> 7;
  const int q0 = (blockIdx.x & 127) << 4;

  // --- mask layout detection: bool bytes vs int32 (deterministic for fixed input) ---
  int myv = 0;
  if (tid < 256) myv = (reinterpret_cast<const unsigned int*>(maskp)[tid] > 1u) ? 1 : 0;
  const int mask_is_byte = __syncthreads_or(myv);

  const int w   = tid >> 6;    // wave 0..7
  const int l   = tid & 63;
  const int l16 = l & 15;
  const int lq  = l >> 4;      // quarter-wave 0..3

  // --- stage Q tile (bf16, XOR-swizzled rows for conflict-free b128 frag reads) ---
  {
    int row = tid >> 5;              // 0..15
    int col = (tid & 31) << 2;       // 0..124 step 4
    u16x4 qv = *reinterpret_cast<const u16x4*>(
        qbf + (((size_t)(b * S_ + q0 + row)) << 7) + col);
    int byte = row * 256 + ((col * 2) ^ ((row & 7) << 4));
    *reinterpret_cast<u16x4*>(reinterpret_cast<char*>(q_lds) + byte) = qv;
  }
  __syncthreads();

  // --- Q B-frags (held in regs for all of pass A) ---
  short8 qf[4];
  {
    int qrow = l16;
#pragma unroll
    for (int ks = 0; ks < 4; ks++) {
      int cb = (lq * 8 + ks * 32) * 2;
      int byte = qrow * 256 + (cb ^ ((qrow & 7) << 4));
      qf[ks] = *reinterpret_cast<const short8*>(
          reinterpret_cast<const char*>(q_lds) + byte);
    }
  }

  const unsigned short* kb = kbf + (((size_t)b * S_) << 7);

  // --- pass A: S^T-fragment MFMA (A=K, B=Q), depth-2 K prefetch ---
  // Lane holds 4 CONSECUTIVE score-columns of one q-row -> single b64 LDS write.
  short8 kf[4], kn[4], knn[4];
  {
    const unsigned short* kp0 = kb + (((size_t)(w * 16 + l16)) << 7) + lq * 8;
    const unsigned short* kp1 = kb + (((size_t)(128 + w * 16 + l16)) << 7) + lq * 8;
#pragma unroll
    for (int ks = 0; ks < 4; ks++) {
      kf[ks] = *reinterpret_cast<const short8*>(kp0 + ks * 32);
      kn[ks] = *reinterpret_cast<const short8*>(kp1 + ks * 32);
    }
  }
  for (int it = 0; it < 16; ++it) {
    if (it + 2 < 16) {
      const unsigned short* kp =
          kb + (((size_t)((it + 2) * 128 + w * 16 + l16)) << 7) + lq * 8;
#pragma unroll
      for (int ks = 0; ks < 4; ks++)
        knn[ks] = *reinterpret_cast<const short8*>(kp + ks * 32);
    }
    f32x4 acc = {0.f, 0.f, 0.f, 0.f};
#pragma unroll
    for (int ks = 0; ks < 4; ks++)
      acc = __builtin_amdgcn_mfma_f32_16x16x32_bf16(kf[ks], qf[ks], acc, 0, 0, 0);
    // D[row=score-col = (l>>4)*4+r][col=q-row = l&15]
    int col = it * 128 + w * 16 + lq * 4;
    u16x4 h;
#pragma unroll
    for (int r = 0; r < 4; r++)
      h[r] = __half_as_ushort(__float2half(acc[r]));
    *reinterpret_cast<u16x4*>(&s_lds[l16][col]) = h;
#pragma unroll
    for (int ks = 0; ks < 4; ks++) { kf[ks] = kn[ks]; kn[ks] = knn[ks]; }
  }
  __syncthreads();

  // --- fused row pass: mask, max, exp once, Z, att write (NT), bf16 P -> LDS ---
  const unsigned char* mask8 = reinterpret_cast<const unsigned char*>(maskp);
  const int* mask32 = reinterpret_cast<const int*>(maskp);
#pragma unroll
  for (int rr = 0; rr < 2; ++rr) {
    const int row = w * 2 + rr;
    const size_t mrow = ((size_t)b * S_ + q0 + row) * S_;
    float s32[32];
    if (mask_is_byte) {
      unsigned int mv[8];
      uint2 sv[8];
#pragma unroll
      for (int it = 0; it < 8; ++it) {   // batch-issue: 8 NT mask + 8 LDS reads
        const int col = it * 256 + l * 4;
        mv[it] = __builtin_nontemporal_load(
            reinterpret_cast<const unsigned int*>(mask8 + mrow + col));
        sv[it] = *reinterpret_cast<const uint2*>(&s_lds[row][col]);
      }
#pragma unroll
      for (int it = 0; it < 8; ++it) {
        float2 f01 = __half22float2(__builtin_bit_cast(__half2, sv[it].x));
        float2 f23 = __half22float2(__builtin_bit_cast(__half2, sv[it].y));
        s32[it * 4 + 0] = (mv[it] & 0x000000ffu) ? -INFINITY : f01.x;
        s32[it * 4 + 1] = (mv[it] & 0x0000ff00u) ? -INFINITY : f01.y;
        s32[it * 4 + 2] = (mv[it] & 0x00ff0000u) ? -INFINITY : f23.x;
        s32[it * 4 + 3] = (mv[it] & 0xff000000u) ? -INFINITY : f23.y;
      }
    } else {
      i32x4 mv[8];
      uint2 sv[8];
#pragma unroll
      for (int it = 0; it < 8; ++it) {
        const int col = it * 256 + l * 4;
        mv[it] = __builtin_nontemporal_load(
            reinterpret_cast<const i32x4*>(mask32 + mrow + col));
        sv[it] = *reinterpret_cast<const uint2*>(&s_lds[row][col]);
      }
#pragma unroll
      for (int it = 0; it < 8; ++it) {
        float2 f01 = __half22float2(__builtin_bit_cast(__half2, sv[it].x));
        float2 f23 = __half22float2(__builtin_bit_cast(__half2, sv[it].y));
        s32[it * 4 + 0] = mv[it][0] ? -INFINITY : f01.x;
        s32[it * 4 + 1] = mv[it][1] ? -INFINITY : f01.y;
        s32[it * 4 + 2] = mv[it][2] ? -INFINITY : f23.x;
        s32[it * 4 + 3] = mv[it][3] ? -INFINITY : f23.y;
      }
    }
    float m = s32[0];
#pragma unroll
    for (int j = 1; j < 32; ++j) m = fmaxf(m, s32[j]);
#pragma unroll
    for (int off = 1; off < 64; off <<= 1) m = fmaxf(m, __shfl_xor(m, off, 64));
    float Z = 0.0f;
#pragma unroll
    for (int j = 0; j < 32; ++j) {
      float e = __expf(s32[j] - m);
      s32[j] = e;
      Z += e;
    }
#pragma unroll
    for (int off = 1; off < 64; off <<= 1) Z += __shfl_xor(Z, off, 64);
    const float iz = 1.0f / Z;
    float* arow = att + mrow;
#pragma unroll
    for (int it = 0; it < 8; ++it) {
      const int col = it * 256 + l * 4;
      f32x4v pv;
      pv[0] = s32[it * 4 + 0] * iz;
      pv[1] = s32[it * 4 + 1] * iz;
      pv[2] = s32[it * 4 + 2] * iz;
      pv[3] = s32[it * 4 + 3] * iz;
      __builtin_nontemporal_store(pv, reinterpret_cast<f32x4v*>(arow + col));
      u16x4 pb;
      pb[0] = f2bf(pv[0]); pb[1] = f2bf(pv[1]);
      pb[2] = f2bf(pv[2]); pb[3] = f2bf(pv[3]);
      *reinterpret_cast<u16x4*>(&s_lds[row][col]) = pb;
    }
  }
  __syncthreads();

  // --- pass C2: context = P V, 2-stage software pipeline (4 k-steps in flight) ---
  {
    const unsigned short* vrow =
        vT + ((size_t)(b * D_ + w * 16 + l16)) * S_ + lq * 8;
    const char* prow = reinterpret_cast<const char*>(&s_lds[l16][0]);
    f32x4 acc0 = {0.f, 0.f, 0.f, 0.f}, acc1 = {0.f, 0.f, 0.f, 0.f};
    short8 a00, a01, b00, b01;   // ks, ks+1
    short8 a10, a11, b10, b11;   // ks+2, ks+3
    a00 = *reinterpret_cast<const short8*>(prow + (lq * 8 + 0 * 32) * 2);
    b00 = *reinterpret_cast<const short8*>(vrow + 0 * 32);
    a01 = *reinterpret_cast<const short8*>(prow + (lq * 8 + 1 * 32) * 2);
    b01 = *reinterpret_cast<const short8*>(vrow + 1 * 32);
    a10 = *reinterpret_cast<const short8*>(prow + (lq * 8 + 2 * 32) * 2);
    b10 = *reinterpret_cast<const short8*>(vrow + 2 * 32);
    a11 = *reinterpret_cast<const short8*>(prow + (lq * 8 + 3 * 32) * 2);
    b11 = *reinterpret_cast<const short8*>(vrow + 3 * 32);
    for (int ks = 0; ks < 64; ks += 2) {
      short8 na0, na1, nb0, nb1;
      if (ks + 4 < 64) {
        na0 = *reinterpret_cast<const short8*>(prow + (lq * 8 + (ks + 4) * 32) * 2);
        nb0 = *reinterpret_cast<const short8*>(vrow + (ks + 4) * 32);
        na1 = *reinterpret_cast<const short8*>(prow + (lq * 8 + (ks + 5) * 32) * 2);
        nb1 = *reinterpret_cast<const short8*>(vrow + (ks + 5) * 32);
      }
      acc0 = __builtin_amdgcn_mfma_f32_16x16x32_bf16(a00, b00, acc0, 0, 0, 0);
      acc1 = __builtin_amdgcn_mfma_f32_16x16x32_bf16(a01, b01, acc1, 0, 0, 0);
      a00 = a10; a01 = a11; b00 = b10; b01 = b11;
      a10 = na0; a11 = na1; b10 = nb0; b11 = nb1;
    }
    float* cb = ctx + ((size_t)(b * S_ + q0)) * D_ + w * 16 + l16;
#pragma unroll
    for (int r = 0; r < 4; r++)
      __builtin_nontemporal_store(acc0[r] + acc1[r],
                                  cb + (size_t)(lq * 4 + r) * D_);
  }
}

extern "C" void kernel_launch(void* const* d_in, const int* in_sizes, int n_in,
                              void* d_out, int out_size, void* d_ws, size_t ws_size,
                              hipStream_t stream) {
  (void)in_sizes; (void)n_in; (void)out_size; (void)ws_size;
  const float* q = (const float*)d_in[0];
  const float* k = (const float*)d_in[1];
  const float* v = (const float*)d_in[2];
  const float* scale = (const float*)d_in[3];
  const void* mask = d_in[4];

  unsigned short* qbf = (unsigned short*)d_ws;                  // 8 MB
  unsigned short* kbf = qbf + (size_t)B_ * S_ * D_;             // 8 MB
  unsigned short* vTb = kbf + (size_t)B_ * S_ * D_;             // 8 MB

  float* ctx = (float*)d_out;                                   // [B,S,D]
  float* att = ctx + (size_t)B_ * S_ * D_;                      // [B,S,S]

  const int n4 = B_ * S_ * D_ / 4;
  cvt_bf16_kernel<<<dim3((n4 + 255) / 256), dim3(256), 0, stream>>>(q, qbf, scale, n4);
  cvt_bf16_kernel<<<dim3((n4 + 255) / 256), dim3(256), 0, stream>>>(k, kbf, nullptr, n4);
  vtrans_kernel<<<dim3(S_ / 32, D_ / 32, B_), dim3(256), 0, stream>>>(v, vTb);
  attn_main_kernel<<<dim3(B_ * (S_ / QB)), dim3(512), 0, stream>>>(
      qbf, kbf, vTb, mask, ctx, att);
}